// Round 1
// baseline (444.539 us; speedup 1.0000x reference)
//
#include <hip/hip_runtime.h>

// Problem constants (from reference):
//   x:       (N=4096, C=64, BH=16, BW=16) f32
//   y_base:  (B=8, C=64, H=512, W=512)    f32
//   indices: (N, 3) int32  [b, r, c],  r0 = r*16, c0 = c*16 (st==bs==16, off==0)
// Output: y_base with x blocks scatter-ADDED (duplicates accumulate).
//
// Strategy: blocks tile the output exactly (16x16 grid of 16x16 tiles per
// (b)). One workgroup per output tile position; scan indices (48KB, L2-hot)
// for matches, then out = y_base + sum(matching x blocks). No atomics.

#define N_BLK  4096
#define C_DIM  64
#define H_DIM  512
#define W_DIM  512
#define BH_DIM 16
#define BW_DIM 16
#define NPOS   (8 * 32 * 32)   // B * H/BH * W/BW = 8192
#define MAXDUP 64

__global__ __launch_bounds__(256) void SparseScatter_fused(
    const float* __restrict__ x,
    const float* __restrict__ yb,
    const int*   __restrict__ idx,
    float*       __restrict__ out,
    int N)
{
    __shared__ int matches[MAXDUP];
    __shared__ int nmatch;

    const int wg = blockIdx.x;
    const int b  = wg >> 10;          // / (32*32)
    const int R  = (wg >> 5) & 31;    // tile row
    const int Cc = wg & 31;           // tile col

    if (threadIdx.x == 0) nmatch = 0;
    __syncthreads();

    // Scan the index list for blocks landing on this tile position.
    for (int n = threadIdx.x; n < N; n += 256) {
        const int bi = idx[3 * n + 0];
        const int ri = idx[3 * n + 1];
        const int ci = idx[3 * n + 2];
        if (bi == b && ri == R && ci == Cc) {
            const int s = atomicAdd(&nmatch, 1);
            if (s < MAXDUP) matches[s] = n;
        }
    }
    __syncthreads();

    int nm = nmatch;
    if (nm > MAXDUP) nm = MAXDUP;

    // Deterministic accumulation order: sort the (tiny) match list.
    if (threadIdx.x == 0 && nm > 1) {
        for (int i = 1; i < nm; ++i) {
            const int key = matches[i];
            int j = i - 1;
            while (j >= 0 && matches[j] > key) { matches[j + 1] = matches[j]; --j; }
            matches[j + 1] = key;
        }
    }
    __syncthreads();

    // Tile region: 64 channels x 16 rows x 16 cols = 4096 floats = 1024 float4.
    // 256 threads x 16 iterations, each iteration one float4.
    const size_t ybase_off =
        ((size_t)b * C_DIM * H_DIM + (size_t)R * BH_DIM) * W_DIM + (size_t)Cc * BW_DIM;

    #pragma unroll
    for (int k = 0; k < 16; ++k) {
        const int lin  = k * 256 + threadIdx.x;  // 0..4095
        const int c    = lin >> 6;               // channel 0..63
        const int q    = lin & 63;               // float4 index within 16x16 tile
        const int row  = q >> 2;                 // 0..15
        const int col  = (q & 3) << 2;           // 0,4,8,12

        const size_t yoff = ybase_off + ((size_t)c * H_DIM + row) * W_DIM + col;

        float4 v = *(const float4*)(yb + yoff);
        for (int m = 0; m < nm; ++m) {
            const int n = matches[m];
            const float4 xv = *(const float4*)(x + (((size_t)n * C_DIM + c) << 8) + (q << 2));
            v.x += xv.x; v.y += xv.y; v.z += xv.z; v.w += xv.w;
        }
        *(float4*)(out + yoff) = v;
    }
}

extern "C" void kernel_launch(void* const* d_in, const int* in_sizes, int n_in,
                              void* d_out, int out_size, void* d_ws, size_t ws_size,
                              hipStream_t stream) {
    const float* x   = (const float*)d_in[0];
    const float* yb  = (const float*)d_in[1];
    const int*   idx = (const int*)d_in[2];
    float*       out = (float*)d_out;

    const int N = in_sizes[2] / 3;   // 4096

    SparseScatter_fused<<<NPOS, 256, 0, stream>>>(x, yb, idx, out, N);
}

// Round 3
// 321.795 us; speedup vs baseline: 1.3814x; 1.3814x over previous
//
#include <hip/hip_runtime.h>

// Problem:
//   x:       (N=4096, C=64, 16, 16) f32   -> x[n,c,i,j] at n*16384 + c*256 + i*16 + j
//   y_base:  (B=8, C=64, H=512, W=512) f32
//   indices: (N,3) int32 [b, r, c]; block origin (r*16, c*16); st==bs==16, off==0
//   out = y_base; out[b, :, r*16+i, c*16+j] += x[n, :, i, j]  (duplicates accumulate)
//
// Blocks tile the output exactly (8192 positions). Strategy:
//   prep (tiny): invert indices into per-position match lists in d_ws
//                (zero counts -> atomic append -> sort for deterministic fp order)
//   main: pure streaming kernel in output-linear order; one thread = one float4.
//         count/slot metadata (544 KB) is L2-resident.

#define NPOS   8192          // 8 * 32 * 32
#define MAXDUP 16            // Poisson(0.5) over 8192 bins: max ~6; 16 is ample
#define OUT4   33554432      // 8*64*512*512 / 4

__global__ void zero_counts(int* __restrict__ cnt) {
    int i = blockIdx.x * 256 + threadIdx.x;
    if (i < NPOS) cnt[i] = 0;
}

__global__ void build_lists(const int* __restrict__ idx, int* __restrict__ cnt,
                            int* __restrict__ slots, int N) {
    int n = blockIdx.x * 256 + threadIdx.x;
    if (n >= N) return;
    const int b = idx[3 * n], r = idx[3 * n + 1], c = idx[3 * n + 2];
    const int pos = b * 1024 + r * 32 + c;
    const int s = atomicAdd(&cnt[pos], 1);
    if (s < MAXDUP) slots[pos * MAXDUP + s] = n;
}

// Sort each (tiny) list ascending so f32 accumulation order is deterministic.
__global__ void sort_lists(const int* __restrict__ cnt, int* __restrict__ slots) {
    int p = blockIdx.x * 256 + threadIdx.x;
    if (p >= NPOS) return;
    int nm = cnt[p]; if (nm > MAXDUP) nm = MAXDUP;
    int* s = slots + p * MAXDUP;
    for (int i = 1; i < nm; ++i) {
        const int key = s[i];
        int j = i - 1;
        while (j >= 0 && s[j] > key) { s[j + 1] = s[j]; --j; }
        s[j + 1] = key;
    }
}

__global__ __launch_bounds__(256) void scatter_main(
    const float4* __restrict__ x4,
    const float4* __restrict__ yb4,
    const int*    __restrict__ cnt,
    const int*    __restrict__ slots,
    float4*       __restrict__ out4)
{
    const int o4 = blockIdx.x * 256 + threadIdx.x;   // < 2^25, fits int

    // o4 bit layout: [b:3][c:6][h:9][w4:7]  (w4 = float4 index within row)
    // pos = b*1024 + (h>>4)*32 + (w>>4)
    const int pos = (o4 >> 22) * 1024 + ((o4 >> 11) & 31) * 32 + ((o4 >> 2) & 31);

    float4 v = yb4[o4];

    int nm = cnt[pos];
    if (nm) {
        if (nm > MAXDUP) nm = MAXDUP;
        // float4 offset within an x block: c*64 + (h&15)*4 + (w4&3)
        const int base = ((o4 >> 16) & 63) * 64 + ((o4 >> 7) & 15) * 4 + (o4 & 3);
        const int* __restrict__ sl = slots + pos * MAXDUP;
        for (int m = 0; m < nm; ++m) {
            const int n = sl[m];
            const float4 xv = x4[n * 4096 + base];
            v.x += xv.x; v.y += xv.y; v.z += xv.z; v.w += xv.w;
        }
    }
    out4[o4] = v;
}

extern "C" void kernel_launch(void* const* d_in, const int* in_sizes, int n_in,
                              void* d_out, int out_size, void* d_ws, size_t ws_size,
                              hipStream_t stream) {
    const float* x   = (const float*)d_in[0];
    const float* yb  = (const float*)d_in[1];
    const int*   idx = (const int*)d_in[2];
    float*       out = (float*)d_out;

    const int N = in_sizes[2] / 3;   // 4096

    // ws layout: int cnt[NPOS]; int slots[NPOS*MAXDUP]  (32 KB + 512 KB)
    int* cnt   = (int*)d_ws;
    int* slots = cnt + NPOS;

    zero_counts<<<(NPOS + 255) / 256, 256, 0, stream>>>(cnt);
    build_lists<<<(N + 255) / 256, 256, 0, stream>>>(idx, cnt, slots, N);
    sort_lists<<<(NPOS + 255) / 256, 256, 0, stream>>>(cnt, slots);

    scatter_main<<<OUT4 / 256, 256, 0, stream>>>(
        (const float4*)x, (const float4*)yb, cnt, slots, (float4*)out);
}

// Round 4
// 265.204 us; speedup vs baseline: 1.6762x; 1.2134x over previous
//
#include <hip/hip_runtime.h>

// Problem:
//   x:       (N=4096, C=64, 16, 16) f32
//   y_base:  (B=8, C=64, H=512, W=512) f32
//   indices: (N,3) int32 [b, r, c]; block origin (r*16, c*16); st==bs==16, off==0
//   out = y_base; out[b, :, r*16+i, c*16+j] += x[n, :, i, j]  (dups accumulate)
//
// Inverted-list + output-linear streaming. This round: 4-wide per-thread
// batching (MLP) + nontemporal yb-load / out-store (keep L3 for x).

#define NPOS   8192
#define MAXDUP 16
#define OUT4   33554432            // 8*64*512*512 / 4
#define WGS    2048
#define CHUNK  (OUT4 / WGS)        // 16384 float4 per WG (256 KB)

typedef float v4f __attribute__((ext_vector_type(4)));

__global__ void zero_counts(int* __restrict__ cnt) {
    int i = blockIdx.x * 256 + threadIdx.x;
    if (i < NPOS) cnt[i] = 0;
}

__global__ void build_lists(const int* __restrict__ idx, int* __restrict__ cnt,
                            int* __restrict__ slots, int N) {
    int n = blockIdx.x * 256 + threadIdx.x;
    if (n >= N) return;
    const int b = idx[3 * n], r = idx[3 * n + 1], c = idx[3 * n + 2];
    const int pos = b * 1024 + r * 32 + c;
    const int s = atomicAdd(&cnt[pos], 1);
    if (s < MAXDUP) slots[pos * MAXDUP + s] = n;
}

__global__ void sort_lists(const int* __restrict__ cnt, int* __restrict__ slots) {
    int p = blockIdx.x * 256 + threadIdx.x;
    if (p >= NPOS) return;
    int nm = cnt[p]; if (nm > MAXDUP) nm = MAXDUP;
    int* s = slots + p * MAXDUP;
    for (int i = 1; i < nm; ++i) {
        const int key = s[i];
        int j = i - 1;
        while (j >= 0 && s[j] > key) { s[j + 1] = s[j]; --j; }
        s[j + 1] = key;
    }
}

__device__ __forceinline__ int pos_of(int i) {
    // i (float4 idx) bits: [b:3][c:6][h:9][w4:7]
    return (i >> 22) * 1024 + ((i >> 11) & 31) * 32 + ((i >> 2) & 31);
}
__device__ __forceinline__ int xbase_of(int i) {
    // float4 offset inside an x block: c*64 + (h&15)*4 + (w4&3)
    return ((i >> 16) & 63) * 64 + ((i >> 7) & 15) * 4 + (i & 3);
}

__global__ __launch_bounds__(256) void scatter_main(
    const v4f* __restrict__ x4,
    const v4f* __restrict__ yb4,
    const int* __restrict__ cnt,
    const int* __restrict__ slots,
    v4f*       __restrict__ out4)
{
    const int base = blockIdx.x * CHUNK + threadIdx.x;

    #pragma unroll 1
    for (int k = 0; k < CHUNK / 256; k += 4) {
        const int i0 = base + (k + 0) * 256;
        const int i1 = base + (k + 1) * 256;
        const int i2 = base + (k + 2) * 256;
        const int i3 = base + (k + 3) * 256;

        // 4 independent streaming loads in flight
        v4f v0 = __builtin_nontemporal_load(yb4 + i0);
        v4f v1 = __builtin_nontemporal_load(yb4 + i1);
        v4f v2 = __builtin_nontemporal_load(yb4 + i2);
        v4f v3 = __builtin_nontemporal_load(yb4 + i3);

        const int p0 = pos_of(i0), p1 = pos_of(i1), p2 = pos_of(i2), p3 = pos_of(i3);
        int n0 = cnt[p0], n1 = cnt[p1], n2 = cnt[p2], n3 = cnt[p3];

        if (n0) {
            if (n0 > MAXDUP) n0 = MAXDUP;
            const int bx = xbase_of(i0);
            const int* __restrict__ sl = slots + p0 * MAXDUP;
            for (int m = 0; m < n0; ++m) v0 += x4[sl[m] * 4096 + bx];
        }
        if (n1) {
            if (n1 > MAXDUP) n1 = MAXDUP;
            const int bx = xbase_of(i1);
            const int* __restrict__ sl = slots + p1 * MAXDUP;
            for (int m = 0; m < n1; ++m) v1 += x4[sl[m] * 4096 + bx];
        }
        if (n2) {
            if (n2 > MAXDUP) n2 = MAXDUP;
            const int bx = xbase_of(i2);
            const int* __restrict__ sl = slots + p2 * MAXDUP;
            for (int m = 0; m < n2; ++m) v2 += x4[sl[m] * 4096 + bx];
        }
        if (n3) {
            if (n3 > MAXDUP) n3 = MAXDUP;
            const int bx = xbase_of(i3);
            const int* __restrict__ sl = slots + p3 * MAXDUP;
            for (int m = 0; m < n3; ++m) v3 += x4[sl[m] * 4096 + bx];
        }

        __builtin_nontemporal_store(v0, out4 + i0);
        __builtin_nontemporal_store(v1, out4 + i1);
        __builtin_nontemporal_store(v2, out4 + i2);
        __builtin_nontemporal_store(v3, out4 + i3);
    }
}

extern "C" void kernel_launch(void* const* d_in, const int* in_sizes, int n_in,
                              void* d_out, int out_size, void* d_ws, size_t ws_size,
                              hipStream_t stream) {
    const float* x   = (const float*)d_in[0];
    const float* yb  = (const float*)d_in[1];
    const int*   idx = (const int*)d_in[2];
    float*       out = (float*)d_out;

    const int N = in_sizes[2] / 3;   // 4096

    int* cnt   = (int*)d_ws;
    int* slots = cnt + NPOS;

    zero_counts<<<(NPOS + 255) / 256, 256, 0, stream>>>(cnt);
    build_lists<<<(N + 255) / 256, 256, 0, stream>>>(idx, cnt, slots, N);
    sort_lists<<<(NPOS + 255) / 256, 256, 0, stream>>>(cnt, slots);

    scatter_main<<<WGS, 256, 0, stream>>>(
        (const v4f*)x, (const v4f*)yb, cnt, slots, (v4f*)out);
}